// Round 16
// baseline (198.082 us; speedup 1.0000x reference)
//
#include <hip/hip_runtime.h>
#include <hip/hip_bf16.h>

#define NUM_USERS 60000
#define NUM_ITEMS 30000
#define N_NODES   90000
#define EDIM      64
#define NEDGES    1000000

#define BKSZ      256                                  // nodes per bucket
#define NBUK      ((N_NODES + BKSZ - 1) / BKSZ)        // 352
#define CHUNK_E   4096                                 // edges per binning block
#define CHUNK_I   (CHUNK_E * 2)                        // directed instances
#define ZROW      N_NODES                              // sentinel zero row index
#define BLKA      512                                  // binning block size (occupancy)

typedef float v2f __attribute__((ext_vector_type(2)));
typedef float v4f __attribute__((ext_vector_type(4)));
typedef unsigned int v4u __attribute__((ext_vector_type(4)));

// bf16 helpers: unpack via shift (exact), pack via RNE
__device__ __forceinline__ float bf_lo(unsigned int u) {
    return __builtin_bit_cast(float, u << 16);
}
__device__ __forceinline__ float bf_hi(unsigned int u) {
    return __builtin_bit_cast(float, u & 0xffff0000u);
}
__device__ __forceinline__ unsigned int f2bf(float f) {
    unsigned int u = __builtin_bit_cast(unsigned int, f);
    return (u + 0x7fffu + ((u >> 16) & 1u)) >> 16;      // RNE to bf16 bits
}

// ---------------------------------------------------------------- combined zero-init:
// bucket counters + sentinel zero rows of both embS buffers (one dispatch)
__global__ void zinit_kernel(int* __restrict__ bc,
                             unsigned int* __restrict__ z0,
                             unsigned int* __restrict__ z1) {
    int i = blockIdx.x * blockDim.x + threadIdx.x;
    if (i < NBUK) bc[i] = 0;
    if (i < EDIM / 2) { z0[i] = 0u; z1[i] = 0u; }
}

// ---------------------------------------------------------------- pass A1: bucket-count histogram
__global__ void histA_kernel(const int* __restrict__ ei, int* __restrict__ bucket_cnt, int E) {
    __shared__ int hist[NBUK];
    int tid = threadIdx.x;
    for (int b = tid; b < NBUK; b += BLKA) hist[b] = 0;
    __syncthreads();
    int e0 = blockIdx.x * CHUNK_E;
    int ecnt = E - e0; if (ecnt > CHUNK_E) ecnt = CHUNK_E;
    for (int k = tid; k < ecnt; k += BLKA) {
        int r = ei[e0 + k];
        int c = ei[E + e0 + k];
        atomicAdd(&hist[c >> 8], 1);
        atomicAdd(&hist[r >> 8], 1);
    }
    __syncthreads();
    for (int b = tid; b < NBUK; b += BLKA)
        if (hist[b] > 0) atomicAdd(&bucket_cnt[b], hist[b]);
}

// ---------------------------------------------------------------- bucket scan (352 values), wave-parallel
__global__ void bscan_kernel(const int* __restrict__ bucket_cnt,
                             int* __restrict__ bucket_base, int* __restrict__ gcursor) {
    int lane = threadIdx.x;            // one wave (64 threads)
    if (lane >= 64) return;
    int carry = 0;
    for (int c = 0; c < (NBUK + 63) / 64; ++c) {
        int i = c * 64 + lane;
        int v = (i < NBUK) ? bucket_cnt[i] : 0;
        int x = v;
        for (int off = 1; off < 64; off <<= 1) {
            int t = __shfl_up(x, off);
            if (lane >= off) x += t;
        }
        if (i < NBUK) {
            int excl = carry + x - v;
            bucket_base[i] = excl;
            gcursor[i]     = excl;
        }
        carry += __shfl(x, 63);
    }
    if (lane == 0) bucket_base[NBUK] = carry;   // == 2*NEDGES
}

// ---------------------------------------------------------------- pass A2: bin edges by dst bucket
// payload u32 = src | (dst_local << 17)
__global__ void binA_kernel(const int* __restrict__ ei, int* __restrict__ gcursor,
                            unsigned int* __restrict__ staged, int E) {
    __shared__ int hist[NBUK];
    __shared__ int lexcl[NBUK + 1];
    __shared__ int cursor[NBUK];
    __shared__ int gbase[NBUK];
    __shared__ unsigned short slotbuk[CHUNK_I];
    __shared__ unsigned int   stage[CHUNK_I];

    int tid = threadIdx.x;
    int e0  = blockIdx.x * CHUNK_E;
    int ecnt = E - e0; if (ecnt > CHUNK_E) ecnt = CHUNK_E;
    int icnt = ecnt * 2;

    for (int b = tid; b < NBUK; b += BLKA) hist[b] = 0;
    __syncthreads();

    for (int k = tid; k < ecnt; k += BLKA) {
        int r = ei[e0 + k];
        int c = ei[E + e0 + k];
        atomicAdd(&hist[c >> 8], 1);
        atomicAdd(&hist[r >> 8], 1);
    }
    __syncthreads();

    // wave-parallel exclusive scan of 352 counts (first wave only)
    if (tid < 64) {
        int carry = 0;
        for (int c = 0; c < (NBUK + 63) / 64; ++c) {
            int i = c * 64 + tid;
            int v = (i < NBUK) ? hist[i] : 0;
            int x = v;
            for (int off = 1; off < 64; off <<= 1) {
                int t = __shfl_up(x, off);
                if (tid >= off) x += t;
            }
            if (i < NBUK) lexcl[i] = carry + x - v;
            carry += __shfl(x, 63);
        }
        if (tid == 0) lexcl[NBUK] = carry;
    }
    __syncthreads();

    for (int b = tid; b < NBUK; b += BLKA) {
        cursor[b] = lexcl[b];
        if (hist[b] > 0) gbase[b] = atomicAdd(&gcursor[b], hist[b]);
    }
    for (int b = tid; b < NBUK; b += BLKA)
        for (int j = lexcl[b]; j < lexcl[b + 1]; ++j) slotbuk[j] = (unsigned short)b;
    __syncthreads();

    for (int k = tid; k < ecnt; k += BLKA) {
        int r = ei[e0 + k];
        int c = ei[E + e0 + k];
        int p1 = atomicAdd(&cursor[c >> 8], 1);
        stage[p1] = (unsigned int)r | ((unsigned int)(c & (BKSZ - 1)) << 17);
        int p2 = atomicAdd(&cursor[r >> 8], 1);
        stage[p2] = (unsigned int)c | ((unsigned int)(r & (BKSZ - 1)) << 17);
    }
    __syncthreads();

    for (int j = tid; j < icnt; j += BLKA) {
        int b = slotbuk[j];
        staged[gbase[b] + (j - lexcl[b])] = stage[j];
    }
}

// ---------------------------------------------------------------- pass B: per-bucket finalize + init
__global__ void binB_kernel(const int* __restrict__ bucket_base,
                            const unsigned int* __restrict__ staged,
                            int* __restrict__ csr_src, int* __restrict__ row_ptr,
                            float* __restrict__ dinv,
                            const float* __restrict__ user_emb,
                            const float* __restrict__ item_emb,
                            unsigned int* __restrict__ embS0,
                            float* __restrict__ out) {
    __shared__ int   deghist[BKSZ];
    __shared__ int   lpre[BKSZ];
    __shared__ int   cur[BKSZ];
    __shared__ float dvs[BKSZ];
    int b = blockIdx.x;
    int node0 = b * BKSZ;
    int nn = N_NODES - node0; if (nn > BKSZ) nn = BKSZ;
    int tid = threadIdx.x;                      // 512 threads
    if (tid < BKSZ) deghist[tid] = 0;
    __syncthreads();
    int base = bucket_base[b];
    int cnt  = bucket_base[b + 1] - base;
    for (int j = tid; j < cnt; j += 512) {
        unsigned int v = staged[base + j];
        atomicAdd(&deghist[v >> 17], 1);
    }
    __syncthreads();
    int myv = (tid < BKSZ) ? deghist[tid] : 0;
    if (tid < BKSZ) lpre[tid] = myv;
    __syncthreads();
    for (int off = 1; off < BKSZ; off <<= 1) {
        int t = (tid < BKSZ && tid >= off) ? lpre[tid - off] : 0;
        __syncthreads();
        if (tid < BKSZ) lpre[tid] += t;
        __syncthreads();
    }
    if (tid < BKSZ) {
        int excl = lpre[tid] - myv;
        cur[tid] = base + excl;
        float dv = (myv > 0) ? (1.0f / sqrtf((float)myv)) : 0.0f;
        dvs[tid] = dv;
        if (tid < nn) {
            row_ptr[node0 + tid] = base + excl;
            dinv[node0 + tid] = dv;
        }
    }
    if (b == NBUK - 1 && tid == 0) row_ptr[N_NODES] = base + cnt;
    __syncthreads();
    for (int j = tid; j < cnt; j += 512) {
        unsigned int v = staged[base + j];
        int pos = atomicAdd(&cur[v >> 17], 1);
        csr_src[pos] = (int)(v & 0x1FFFFu);     // scattered only within ~23KB region
    }
    // fused init for this bucket's nodes: out = emb0, embS0 = bf16(dv*emb0)
    for (int k = tid; k < nn * 16; k += 512) {
        int loc = k >> 4;
        int node = node0 + loc;
        int gi = node * 16 + (k & 15);          // float4 index
        float4 e = (node < NUM_USERS) ? ((const float4*)user_emb)[gi]
                                      : ((const float4*)item_emb)[gi - NUM_USERS * 16];
        ((float4*)out)[gi] = e;
        float dvv = dvs[loc];
        uint2 p;
        p.x = f2bf(dvv * e.x) | (f2bf(dvv * e.y) << 16);
        p.y = f2bf(dvv * e.z) | (f2bf(dvv * e.w) << 16);
        ((uint2*)embS0)[gi] = p;
    }
}

// ---------------------------------------------------------------- propagation layer, phased
// node0/ncount select user phase (0,60000: gathers 3.84MB item table -> fits a
// per-XCD L2) or item phase (60000,30000: gathers 7.7MB user table). All
// streaming epilogue traffic (out RMW, embS_out write) is NONTEMPORAL so it
// does not write-allocate in L2 and evict the gather table -- the suspected
// reason the R9 split showed no win. Inner loop = R15 (quad-issue, pinned).
#define GISSUE(TT, U)                                                   \
    {                                                                   \
        int _src = __shfl(mysrc, (TT));                                 \
        U = *(const uint4*)(tabl + ((unsigned)_src << 7));              \
    }
#define GACC(U)                                                         \
    {                                                                   \
        a0 += (v2f){bf_lo((U).x), bf_hi((U).x)};                        \
        a1 += (v2f){bf_lo((U).y), bf_hi((U).y)};                        \
        a2 += (v2f){bf_lo((U).z), bf_hi((U).z)};                        \
        a3 += (v2f){bf_lo((U).w), bf_hi((U).w)};                        \
    }

template <int LAST>
__global__ __launch_bounds__(256, 8) void layer_kernel(
                             const int* __restrict__ row_ptr,
                             const int* __restrict__ csr_src,
                             const float* __restrict__ dinv,
                             const unsigned int* __restrict__ embS_in,   // bf16x2 words
                             unsigned int* __restrict__ embS_out,
                             float* __restrict__ out,
                             int node0, int ncount) {
    int w    = (blockIdx.x * blockDim.x + threadIdx.x) >> 6;
    int lane = threadIdx.x & 63;
    if (w >= ncount) return;
    int node = node0 + w;
    int g  = lane >> 3;          // source slot within step (0..7)
    int sl = lane & 7;           // uint4 index within row (dims 8*sl..8*sl+7)
    int start = row_ptr[node];
    int end   = row_ptr[node + 1];
    v2f a0 = {0.f, 0.f}, a1 = {0.f, 0.f}, a2 = {0.f, 0.f}, a3 = {0.f, 0.f};

    const char* tabl = (const char*)embS_in + (sl << 4);   // lane's 16B slot base

    for (int j0 = start; j0 < end; j0 += 64) {
        int idx   = j0 + lane;
        int mysrc = (idx < end) ? csr_src[idx] : ZROW;   // sentinel for tail slots
        int cnt   = min(64, end - j0);
        int nstep = (cnt + 7) >> 3;                      // 1..8 steps of 8 sources
        int tb = g;
        for (int sb = 0; sb < nstep; sb += 4) {
            uint4 ua, ub, uc, ud;
            GISSUE(tb,      ua)
            GISSUE(tb +  8, ub)                          // overshoot -> sentinel row
            GISSUE(tb + 16, uc)
            GISSUE(tb + 24, ud)
            __builtin_amdgcn_sched_barrier(0);           // pin: all 4 loads issued first
            GACC(ua)
            GACC(ub)
            GACC(uc)
            GACC(ud)
            tb += 32;
        }
    }

    float s0 = a0.x, s1 = a0.y, s2 = a1.x, s3 = a1.y;
    float s4 = a2.x, s5 = a2.y, s6 = a3.x, s7 = a3.y;

    // reduce the 8 lane-groups (lanes differing in bits 3,4,5)
    s0 += __shfl_xor(s0, 8); s0 += __shfl_xor(s0, 16); s0 += __shfl_xor(s0, 32);
    s1 += __shfl_xor(s1, 8); s1 += __shfl_xor(s1, 16); s1 += __shfl_xor(s1, 32);
    s2 += __shfl_xor(s2, 8); s2 += __shfl_xor(s2, 16); s2 += __shfl_xor(s2, 32);
    s3 += __shfl_xor(s3, 8); s3 += __shfl_xor(s3, 16); s3 += __shfl_xor(s3, 32);
    s4 += __shfl_xor(s4, 8); s4 += __shfl_xor(s4, 16); s4 += __shfl_xor(s4, 32);
    s5 += __shfl_xor(s5, 8); s5 += __shfl_xor(s5, 16); s5 += __shfl_xor(s5, 32);
    s6 += __shfl_xor(s6, 8); s6 += __shfl_xor(s6, 16); s6 += __shfl_xor(s6, 32);
    s7 += __shfl_xor(s7, 8); s7 += __shfl_xor(s7, 16); s7 += __shfl_xor(s7, 32);

    if (lane < 8) {                              // lane sl owns dims 8*sl..8*sl+7
        float dv = dinv[node];
        float e0 = dv * s0, e1 = dv * s1, e2 = dv * s2, e3 = dv * s3;
        float e4 = dv * s4, e5 = dv * s5, e6 = dv * s6, e7 = dv * s7;
        size_t f4 = ((size_t)node << 4) + 2 * sl;     // float4 index
        v4f p0 = __builtin_nontemporal_load((const v4f*)out + f4);
        v4f p1 = __builtin_nontemporal_load((const v4f*)out + f4 + 1);
        if (LAST) {
            p0 = (p0 + (v4f){e0, e1, e2, e3}) * 0.25f;
            p1 = (p1 + (v4f){e4, e5, e6, e7}) * 0.25f;
            __builtin_nontemporal_store(p0, (v4f*)out + f4);
            __builtin_nontemporal_store(p1, (v4f*)out + f4 + 1);
        } else {
            p0 += (v4f){e0, e1, e2, e3};
            p1 += (v4f){e4, e5, e6, e7};
            __builtin_nontemporal_store(p0, (v4f*)out + f4);
            __builtin_nontemporal_store(p1, (v4f*)out + f4 + 1);
            v4u q;                                // embS_out = bf16(dv*e)
            q.x = f2bf(dv * e0) | (f2bf(dv * e1) << 16);
            q.y = f2bf(dv * e2) | (f2bf(dv * e3) << 16);
            q.z = f2bf(dv * e4) | (f2bf(dv * e5) << 16);
            q.w = f2bf(dv * e6) | (f2bf(dv * e7) << 16);
            __builtin_nontemporal_store(q, (v4u*)embS_out + ((size_t)node << 3) + sl);
        }
    }
}

// ----------------------------------------------------------------
extern "C" void kernel_launch(void* const* d_in, const int* in_sizes, int n_in,
                              void* d_out, int out_size, void* d_ws, size_t ws_size,
                              hipStream_t stream) {
    const int*   ei       = (const int*)d_in[0];
    const float* user_emb = (const float*)d_in[1];
    const float* item_emb = (const float*)d_in[2];
    float*       out      = (float*)d_out;

    char* ws = (char*)d_ws;
    size_t off = 0;
    auto alloc = [&](size_t bytes) -> void* {
        void* p = ws + off;
        off = (off + bytes + 255) & ~(size_t)255;
        return p;
    };

    int*   bucket_cnt  = (int*)  alloc((size_t)NBUK * 4);
    int*   bucket_base = (int*)  alloc(((size_t)NBUK + 1) * 4);
    int*   gcursor     = (int*)  alloc((size_t)NBUK * 4);
    int*   row_ptr     = (int*)  alloc(((size_t)N_NODES + 1) * 4);
    float* dinv        = (float*)alloc((size_t)N_NODES * 4);
    unsigned int* staged = (unsigned int*)alloc((size_t)2 * NEDGES * 4);
    int*   csr_src     = (int*)  alloc((size_t)2 * NEDGES * 4);
    // +1 sentinel zero row each
    unsigned int* embS0 = (unsigned int*)alloc((size_t)(N_NODES + 1) * EDIM * 2);
    unsigned int* embS1 = (unsigned int*)alloc((size_t)(N_NODES + 1) * EDIM * 2);

    const int B = 256;
    zinit_kernel<<<2, B, 0, stream>>>(bucket_cnt,
                                      embS0 + (size_t)ZROW * (EDIM / 2),
                                      embS1 + (size_t)ZROW * (EDIM / 2));

    int nbin = (NEDGES + CHUNK_E - 1) / CHUNK_E;   // 245
    histA_kernel<<<nbin, BLKA, 0, stream>>>(ei, bucket_cnt, NEDGES);
    bscan_kernel<<<1, 64, 0, stream>>>(bucket_cnt, bucket_base, gcursor);
    binA_kernel<<<nbin, BLKA, 0, stream>>>(ei, gcursor, staged, NEDGES);
    binB_kernel<<<NBUK, 512, 0, stream>>>(bucket_base, staged, csr_src, row_ptr, dinv,
                                          user_emb, item_emb, embS0, out);

    int ugrid = NUM_USERS * 64 / B;   // 15000 blocks
    int igrid = NUM_ITEMS * 64 / B;   // 7500 blocks

    // layer 1
    layer_kernel<0><<<ugrid, B, 0, stream>>>(row_ptr, csr_src, dinv, embS0, embS1, out, 0, NUM_USERS);
    layer_kernel<0><<<igrid, B, 0, stream>>>(row_ptr, csr_src, dinv, embS0, embS1, out, NUM_USERS, NUM_ITEMS);
    // layer 2
    layer_kernel<0><<<ugrid, B, 0, stream>>>(row_ptr, csr_src, dinv, embS1, embS0, out, 0, NUM_USERS);
    layer_kernel<0><<<igrid, B, 0, stream>>>(row_ptr, csr_src, dinv, embS1, embS0, out, NUM_USERS, NUM_ITEMS);
    // layer 3 (fused mean)
    layer_kernel<1><<<ugrid, B, 0, stream>>>(row_ptr, csr_src, dinv, embS0, nullptr, out, 0, NUM_USERS);
    layer_kernel<1><<<igrid, B, 0, stream>>>(row_ptr, csr_src, dinv, embS0, nullptr, out, NUM_USERS, NUM_ITEMS);
}

// Round 17
// 175.420 us; speedup vs baseline: 1.1292x; 1.1292x over previous
//
#include <hip/hip_runtime.h>
#include <hip/hip_bf16.h>

#define NUM_USERS 60000
#define NUM_ITEMS 30000
#define N_NODES   90000
#define EDIM      64
#define NEDGES    1000000

#define BKSZ      256                                  // nodes per bucket
#define NBUK      ((N_NODES + BKSZ - 1) / BKSZ)        // 352
#define CHUNK_E   4096                                 // edges per binning block
#define CHUNK_I   (CHUNK_E * 2)                        // directed instances
#define ZROW      N_NODES                              // sentinel zero row index
#define BLKA      512                                  // binning block size (occupancy)

typedef float v2f __attribute__((ext_vector_type(2)));

// bf16 helpers: unpack via shift (exact), pack via RNE
__device__ __forceinline__ float bf_lo(unsigned int u) {
    return __builtin_bit_cast(float, u << 16);
}
__device__ __forceinline__ float bf_hi(unsigned int u) {
    return __builtin_bit_cast(float, u & 0xffff0000u);
}
__device__ __forceinline__ unsigned int f2bf(float f) {
    unsigned int u = __builtin_bit_cast(unsigned int, f);
    return (u + 0x7fffu + ((u >> 16) & 1u)) >> 16;      // RNE to bf16 bits
}

// ---------------------------------------------------------------- combined zero-init:
// bucket counters + sentinel zero rows of both embS buffers (one dispatch)
__global__ void zinit_kernel(int* __restrict__ bc,
                             unsigned int* __restrict__ z0,
                             unsigned int* __restrict__ z1) {
    int i = blockIdx.x * blockDim.x + threadIdx.x;
    if (i < NBUK) bc[i] = 0;
    if (i < EDIM / 2) { z0[i] = 0u; z1[i] = 0u; }
}

// ---------------------------------------------------------------- pass A1: bucket-count histogram
__global__ void histA_kernel(const int* __restrict__ ei, int* __restrict__ bucket_cnt, int E) {
    __shared__ int hist[NBUK];
    int tid = threadIdx.x;
    for (int b = tid; b < NBUK; b += BLKA) hist[b] = 0;
    __syncthreads();
    int e0 = blockIdx.x * CHUNK_E;
    int ecnt = E - e0; if (ecnt > CHUNK_E) ecnt = CHUNK_E;
    for (int k = tid; k < ecnt; k += BLKA) {
        int r = ei[e0 + k];
        int c = ei[E + e0 + k];
        atomicAdd(&hist[c >> 8], 1);
        atomicAdd(&hist[r >> 8], 1);
    }
    __syncthreads();
    for (int b = tid; b < NBUK; b += BLKA)
        if (hist[b] > 0) atomicAdd(&bucket_cnt[b], hist[b]);
}

// ---------------------------------------------------------------- bucket scan (352 values), wave-parallel
__global__ void bscan_kernel(const int* __restrict__ bucket_cnt,
                             int* __restrict__ bucket_base, int* __restrict__ gcursor) {
    int lane = threadIdx.x;            // one wave (64 threads)
    if (lane >= 64) return;
    int carry = 0;
    for (int c = 0; c < (NBUK + 63) / 64; ++c) {
        int i = c * 64 + lane;
        int v = (i < NBUK) ? bucket_cnt[i] : 0;
        int x = v;
        for (int off = 1; off < 64; off <<= 1) {
            int t = __shfl_up(x, off);
            if (lane >= off) x += t;
        }
        if (i < NBUK) {
            int excl = carry + x - v;
            bucket_base[i] = excl;
            gcursor[i]     = excl;
        }
        carry += __shfl(x, 63);
    }
    if (lane == 0) bucket_base[NBUK] = carry;   // == 2*NEDGES
}

// ---------------------------------------------------------------- pass A2: bin edges by dst bucket
// payload u32 = src | (dst_local << 17)
__global__ void binA_kernel(const int* __restrict__ ei, int* __restrict__ gcursor,
                            unsigned int* __restrict__ staged, int E) {
    __shared__ int hist[NBUK];
    __shared__ int lexcl[NBUK + 1];
    __shared__ int cursor[NBUK];
    __shared__ int gbase[NBUK];
    __shared__ unsigned short slotbuk[CHUNK_I];
    __shared__ unsigned int   stage[CHUNK_I];

    int tid = threadIdx.x;
    int e0  = blockIdx.x * CHUNK_E;
    int ecnt = E - e0; if (ecnt > CHUNK_E) ecnt = CHUNK_E;
    int icnt = ecnt * 2;

    for (int b = tid; b < NBUK; b += BLKA) hist[b] = 0;
    __syncthreads();

    for (int k = tid; k < ecnt; k += BLKA) {
        int r = ei[e0 + k];
        int c = ei[E + e0 + k];
        atomicAdd(&hist[c >> 8], 1);
        atomicAdd(&hist[r >> 8], 1);
    }
    __syncthreads();

    // wave-parallel exclusive scan of 352 counts (first wave only)
    if (tid < 64) {
        int carry = 0;
        for (int c = 0; c < (NBUK + 63) / 64; ++c) {
            int i = c * 64 + tid;
            int v = (i < NBUK) ? hist[i] : 0;
            int x = v;
            for (int off = 1; off < 64; off <<= 1) {
                int t = __shfl_up(x, off);
                if (tid >= off) x += t;
            }
            if (i < NBUK) lexcl[i] = carry + x - v;
            carry += __shfl(x, 63);
        }
        if (tid == 0) lexcl[NBUK] = carry;
    }
    __syncthreads();

    for (int b = tid; b < NBUK; b += BLKA) {
        cursor[b] = lexcl[b];
        if (hist[b] > 0) gbase[b] = atomicAdd(&gcursor[b], hist[b]);
    }
    for (int b = tid; b < NBUK; b += BLKA)
        for (int j = lexcl[b]; j < lexcl[b + 1]; ++j) slotbuk[j] = (unsigned short)b;
    __syncthreads();

    for (int k = tid; k < ecnt; k += BLKA) {
        int r = ei[e0 + k];
        int c = ei[E + e0 + k];
        int p1 = atomicAdd(&cursor[c >> 8], 1);
        stage[p1] = (unsigned int)r | ((unsigned int)(c & (BKSZ - 1)) << 17);
        int p2 = atomicAdd(&cursor[r >> 8], 1);
        stage[p2] = (unsigned int)c | ((unsigned int)(r & (BKSZ - 1)) << 17);
    }
    __syncthreads();

    for (int j = tid; j < icnt; j += BLKA) {
        int b = slotbuk[j];
        staged[gbase[b] + (j - lexcl[b])] = stage[j];
    }
}

// ---------------------------------------------------------------- pass B: per-bucket finalize + init
__global__ void binB_kernel(const int* __restrict__ bucket_base,
                            const unsigned int* __restrict__ staged,
                            int* __restrict__ csr_src, int* __restrict__ row_ptr,
                            float* __restrict__ dinv,
                            const float* __restrict__ user_emb,
                            const float* __restrict__ item_emb,
                            unsigned int* __restrict__ embS0,
                            float* __restrict__ out) {
    __shared__ int   deghist[BKSZ];
    __shared__ int   lpre[BKSZ];
    __shared__ int   cur[BKSZ];
    __shared__ float dvs[BKSZ];
    int b = blockIdx.x;
    int node0 = b * BKSZ;
    int nn = N_NODES - node0; if (nn > BKSZ) nn = BKSZ;
    int tid = threadIdx.x;                      // 512 threads
    if (tid < BKSZ) deghist[tid] = 0;
    __syncthreads();
    int base = bucket_base[b];
    int cnt  = bucket_base[b + 1] - base;
    for (int j = tid; j < cnt; j += 512) {
        unsigned int v = staged[base + j];
        atomicAdd(&deghist[v >> 17], 1);
    }
    __syncthreads();
    int myv = (tid < BKSZ) ? deghist[tid] : 0;
    if (tid < BKSZ) lpre[tid] = myv;
    __syncthreads();
    for (int off = 1; off < BKSZ; off <<= 1) {
        int t = (tid < BKSZ && tid >= off) ? lpre[tid - off] : 0;
        __syncthreads();
        if (tid < BKSZ) lpre[tid] += t;
        __syncthreads();
    }
    if (tid < BKSZ) {
        int excl = lpre[tid] - myv;
        cur[tid] = base + excl;
        float dv = (myv > 0) ? (1.0f / sqrtf((float)myv)) : 0.0f;
        dvs[tid] = dv;
        if (tid < nn) {
            row_ptr[node0 + tid] = base + excl;
            dinv[node0 + tid] = dv;
        }
    }
    if (b == NBUK - 1 && tid == 0) row_ptr[N_NODES] = base + cnt;
    __syncthreads();
    for (int j = tid; j < cnt; j += 512) {
        unsigned int v = staged[base + j];
        int pos = atomicAdd(&cur[v >> 17], 1);
        csr_src[pos] = (int)(v & 0x1FFFFu);     // scattered only within ~23KB region
    }
    // fused init for this bucket's nodes: out = emb0, embS0 = bf16(dv*emb0)
    for (int k = tid; k < nn * 16; k += 512) {
        int loc = k >> 4;
        int node = node0 + loc;
        int gi = node * 16 + (k & 15);          // float4 index
        float4 e = (node < NUM_USERS) ? ((const float4*)user_emb)[gi]
                                      : ((const float4*)item_emb)[gi - NUM_USERS * 16];
        ((float4*)out)[gi] = e;
        float dvv = dvs[loc];
        uint2 p;
        p.x = f2bf(dvv * e.x) | (f2bf(dvv * e.y) << 16);
        p.y = f2bf(dvv * e.z) | (f2bf(dvv * e.w) << 16);
        ((uint2*)embS0)[gi] = p;
    }
}

// ---------------------------------------------------------------- propagation layer (all nodes)
// Best-known structure (R15, 44.2us/layer). Wave per node; 8 groups of 8 lanes;
// one source row per group per step (uint4, 1KB/instr). Maskless via sentinel
// zero row. Quad-issue with sched_barrier(0) pinning.
#define GISSUE(TT, U)                                                   \
    {                                                                   \
        int _src = __shfl(mysrc, (TT));                                 \
        U = *(const uint4*)(tabl + ((unsigned)_src << 7));              \
    }
#define GACC(U)                                                         \
    {                                                                   \
        a0 += (v2f){bf_lo((U).x), bf_hi((U).x)};                        \
        a1 += (v2f){bf_lo((U).y), bf_hi((U).y)};                        \
        a2 += (v2f){bf_lo((U).z), bf_hi((U).z)};                        \
        a3 += (v2f){bf_lo((U).w), bf_hi((U).w)};                        \
    }

template <int LAST>
__global__ __launch_bounds__(256, 8) void layer_kernel(
                             const int* __restrict__ row_ptr,
                             const int* __restrict__ csr_src,
                             const float* __restrict__ dinv,
                             const unsigned int* __restrict__ embS_in,   // bf16x2 words
                             unsigned int* __restrict__ embS_out,
                             float* __restrict__ out) {
    int node = (blockIdx.x * blockDim.x + threadIdx.x) >> 6;
    int lane = threadIdx.x & 63;
    if (node >= N_NODES) return;
    int g  = lane >> 3;          // source slot within step (0..7)
    int sl = lane & 7;           // uint4 index within row (dims 8*sl..8*sl+7)
    int start = row_ptr[node];
    int end   = row_ptr[node + 1];
    v2f a0 = {0.f, 0.f}, a1 = {0.f, 0.f}, a2 = {0.f, 0.f}, a3 = {0.f, 0.f};

    const char* tabl = (const char*)embS_in + (sl << 4);   // lane's 16B slot base

    for (int j0 = start; j0 < end; j0 += 64) {
        int idx   = j0 + lane;
        int mysrc = (idx < end) ? csr_src[idx] : ZROW;   // sentinel for tail slots
        int cnt   = min(64, end - j0);
        int nstep = (cnt + 7) >> 3;                      // 1..8 steps of 8 sources
        int tb = g;
        for (int sb = 0; sb < nstep; sb += 4) {
            uint4 ua, ub, uc, ud;
            GISSUE(tb,      ua)
            GISSUE(tb +  8, ub)                          // overshoot -> sentinel row
            GISSUE(tb + 16, uc)
            GISSUE(tb + 24, ud)
            __builtin_amdgcn_sched_barrier(0);           // pin: all 4 loads issued first
            GACC(ua)
            GACC(ub)
            GACC(uc)
            GACC(ud)
            tb += 32;
        }
    }

    float s0 = a0.x, s1 = a0.y, s2 = a1.x, s3 = a1.y;
    float s4 = a2.x, s5 = a2.y, s6 = a3.x, s7 = a3.y;

    // reduce the 8 lane-groups (lanes differing in bits 3,4,5)
    s0 += __shfl_xor(s0, 8); s0 += __shfl_xor(s0, 16); s0 += __shfl_xor(s0, 32);
    s1 += __shfl_xor(s1, 8); s1 += __shfl_xor(s1, 16); s1 += __shfl_xor(s1, 32);
    s2 += __shfl_xor(s2, 8); s2 += __shfl_xor(s2, 16); s2 += __shfl_xor(s2, 32);
    s3 += __shfl_xor(s3, 8); s3 += __shfl_xor(s3, 16); s3 += __shfl_xor(s3, 32);
    s4 += __shfl_xor(s4, 8); s4 += __shfl_xor(s4, 16); s4 += __shfl_xor(s4, 32);
    s5 += __shfl_xor(s5, 8); s5 += __shfl_xor(s5, 16); s5 += __shfl_xor(s5, 32);
    s6 += __shfl_xor(s6, 8); s6 += __shfl_xor(s6, 16); s6 += __shfl_xor(s6, 32);
    s7 += __shfl_xor(s7, 8); s7 += __shfl_xor(s7, 16); s7 += __shfl_xor(s7, 32);

    if (lane < 8) {                              // lane sl owns dims 8*sl..8*sl+7
        float dv = dinv[node];
        float e0 = dv * s0, e1 = dv * s1, e2 = dv * s2, e3 = dv * s3;
        float e4 = dv * s4, e5 = dv * s5, e6 = dv * s6, e7 = dv * s7;
        size_t f4 = ((size_t)node << 4) + 2 * sl;     // float4 index
        float4 p0 = ((const float4*)out)[f4];
        float4 p1 = ((const float4*)out)[f4 + 1];
        if (LAST) {
            p0.x = (p0.x + e0) * 0.25f; p0.y = (p0.y + e1) * 0.25f;
            p0.z = (p0.z + e2) * 0.25f; p0.w = (p0.w + e3) * 0.25f;
            p1.x = (p1.x + e4) * 0.25f; p1.y = (p1.y + e5) * 0.25f;
            p1.z = (p1.z + e6) * 0.25f; p1.w = (p1.w + e7) * 0.25f;
            ((float4*)out)[f4]     = p0;
            ((float4*)out)[f4 + 1] = p1;
        } else {
            p0.x += e0; p0.y += e1; p0.z += e2; p0.w += e3;
            p1.x += e4; p1.y += e5; p1.z += e6; p1.w += e7;
            ((float4*)out)[f4]     = p0;
            ((float4*)out)[f4 + 1] = p1;
            uint4 q;                              // embS_out = bf16(dv*e)
            q.x = f2bf(dv * e0) | (f2bf(dv * e1) << 16);
            q.y = f2bf(dv * e2) | (f2bf(dv * e3) << 16);
            q.z = f2bf(dv * e4) | (f2bf(dv * e5) << 16);
            q.w = f2bf(dv * e6) | (f2bf(dv * e7) << 16);
            ((uint4*)embS_out)[((size_t)node << 3) + sl] = q;
        }
    }
}

// ----------------------------------------------------------------
extern "C" void kernel_launch(void* const* d_in, const int* in_sizes, int n_in,
                              void* d_out, int out_size, void* d_ws, size_t ws_size,
                              hipStream_t stream) {
    const int*   ei       = (const int*)d_in[0];
    const float* user_emb = (const float*)d_in[1];
    const float* item_emb = (const float*)d_in[2];
    float*       out      = (float*)d_out;

    char* ws = (char*)d_ws;
    size_t off = 0;
    auto alloc = [&](size_t bytes) -> void* {
        void* p = ws + off;
        off = (off + bytes + 255) & ~(size_t)255;
        return p;
    };

    int*   bucket_cnt  = (int*)  alloc((size_t)NBUK * 4);
    int*   bucket_base = (int*)  alloc(((size_t)NBUK + 1) * 4);
    int*   gcursor     = (int*)  alloc((size_t)NBUK * 4);
    int*   row_ptr     = (int*)  alloc(((size_t)N_NODES + 1) * 4);
    float* dinv        = (float*)alloc((size_t)N_NODES * 4);
    unsigned int* staged = (unsigned int*)alloc((size_t)2 * NEDGES * 4);
    int*   csr_src     = (int*)  alloc((size_t)2 * NEDGES * 4);
    // +1 sentinel zero row each
    unsigned int* embS0 = (unsigned int*)alloc((size_t)(N_NODES + 1) * EDIM * 2);
    unsigned int* embS1 = (unsigned int*)alloc((size_t)(N_NODES + 1) * EDIM * 2);

    const int B = 256;
    zinit_kernel<<<2, B, 0, stream>>>(bucket_cnt,
                                      embS0 + (size_t)ZROW * (EDIM / 2),
                                      embS1 + (size_t)ZROW * (EDIM / 2));

    int nbin = (NEDGES + CHUNK_E - 1) / CHUNK_E;   // 245
    histA_kernel<<<nbin, BLKA, 0, stream>>>(ei, bucket_cnt, NEDGES);
    bscan_kernel<<<1, 64, 0, stream>>>(bucket_cnt, bucket_base, gcursor);
    binA_kernel<<<nbin, BLKA, 0, stream>>>(ei, gcursor, staged, NEDGES);
    binB_kernel<<<NBUK, 512, 0, stream>>>(bucket_base, staged, csr_src, row_ptr, dinv,
                                          user_emb, item_emb, embS0, out);

    int lgrid = N_NODES * 64 / B;   // 22500 blocks, one wave per node
    layer_kernel<0><<<lgrid, B, 0, stream>>>(row_ptr, csr_src, dinv, embS0, embS1, out);
    layer_kernel<0><<<lgrid, B, 0, stream>>>(row_ptr, csr_src, dinv, embS1, embS0, out);
    layer_kernel<1><<<lgrid, B, 0, stream>>>(row_ptr, csr_src, dinv, embS0, nullptr, out);
}